// Round 19
// baseline (149.428 us; speedup 1.0000x reference)
//
#include <hip/hip_runtime.h>
#include <hip/hip_bf16.h>

#define DEV static __device__ __forceinline__

DEV float silu(float x){ return x / (1.f + __expf(-x)); }

typedef __attribute__((ext_vector_type(8))) short bf16x8;
typedef __attribute__((ext_vector_type(4))) float f32x4;

DEV unsigned short f2bf(float f){
    unsigned u = __float_as_uint(f);
    u += 0x7FFF + ((u >> 16) & 1);      // RNE
    return (unsigned short)(u >> 16);
}
DEV float bf(const unsigned short* p){ return __uint_as_float(((unsigned)(*p)) << 16); }

// ---- problem sizes ----
#define BB 4
#define LL 4096          // H*W, H=W=64
#define DM 96
#define DI 192
#define NS 16
#define KK 4
#define RR 6
#define C38 38
#define NC 128           // chunks
#define CL 32            // chunk length
#define NCOMB 224        // combined x_proj/dt_proj rows: 192 delta + 32 B/C

// ---- workspace layout (float offsets); total ~= 98.5 MB ----
#define OFF_XIN   0                              // f32 (conv input precision)
#define OFF_Z     (OFF_XIN + 3145728)            // bf16 (u16 in half slot)
#define OFF_XC    (OFF_Z + 1572864)              // bf16 xcb
#define OFF_DELTA (OFF_XC + 1572864)             // bf16, SPATIAL order
#define OFF_HLOC  (OFF_DELTA + 6291456)          // bf16
#define OFF_BC    (OFF_HLOC + 3145728)           // f32, SPATIAL order
#define OFF_YS    (OFF_BC + 2097152)             // bf16
#define OFF_S     (OFF_YS + 6291456)             // f32
#define OFF_WB    (OFF_S + 393216)               // bf16 in_proj weights
#define OFF_CWT   (OFF_WB + 18432)               // f32 transposed conv weights
#define OFF_WC    (OFF_CWT + 1728)               // bf16 combined x/dt proj weights
#define OFF_WO    (OFF_WC + 86016)               // bf16 out_proj weights

DEV int pos_of(int k, int t){
    int pr = ((t & 63) << 6) | (t >> 6);
    int p  = (k & 1) ? pr : t;
    if (k & 2) p = LL - 1 - p;
    return p;
}

// ---- 0. prep ----
__global__ __launch_bounds__(256) void k_prep(const float* __restrict__ win, const float* __restrict__ cw,
                                              const float* __restrict__ xpw, const float* __restrict__ dtw,
                                              const float* __restrict__ wout,
                                              unsigned short* __restrict__ winb, float* __restrict__ cwT,
                                              unsigned short* __restrict__ wcomb, unsigned short* __restrict__ woutb){
    int i = blockIdx.x * 256 + threadIdx.x;
    if (i < 384*DM) winb[i] = f2bf(win[i]);
    if (i < 9*DI){ int tap = i / DI, d = i - tap*DI; cwT[i] = cw[d*9 + tap]; }
    if (i < DM*DI) woutb[i] = f2bf(wout[i]);
    if (i < KK*NCOMB*DI){
        int kk = i % DI; int j = (i / DI) % NCOMB; int k = i / (DI*NCOMB);
        float v;
        if (j < DI){
            v = 0.f;
            const float* dtwp = dtw + ((long)k*DI + j)*RR;
            const float* xp   = xpw + (long)k*C38*DI + kk;
#pragma unroll
            for (int r = 0; r < RR; ++r) v += dtwp[r] * xp[(long)r*DI];
        } else {
            v = xpw[(long)k*C38*DI + (long)(6 + j - DI)*DI + kk];
        }
        wcomb[i] = f2bf(v);
    }
}

// ---- 1. in_proj: bf16 MFMA GEMM; z out bf16 ----
__global__ __launch_bounds__(256) void k_inproj(const float* __restrict__ x, const unsigned short* __restrict__ winb,
                                                float* __restrict__ xin, unsigned short* __restrict__ zb){
    __shared__ unsigned short xsb[16*104];
    int tid = threadIdx.x;
    int r0 = blockIdx.x * 16;
    const float* xrow = x + (long)r0 * DM;
    for (int i = tid; i < 16*DM; i += 256){
        int r = i / DM, d = i - r*DM;
        xsb[r*104 + d] = f2bf(xrow[i]);
    }
    __syncthreads();
    int wv = tid >> 6, l = tid & 63;
    int lrow = l & 15, kg = l >> 4;
    int nc0 = wv * 96;
    f32x4 acc[6];
#pragma unroll
    for (int j = 0; j < 6; ++j) acc[j] = (f32x4){0,0,0,0};
    const unsigned short* arow = &xsb[lrow*104 + kg*8];
#pragma unroll
    for (int kk = 0; kk < 3; ++kk){
        bf16x8 af = *(const bf16x8*)(arow + kk*32);
#pragma unroll
        for (int j = 0; j < 6; ++j){
            int col = nc0 + j*16 + lrow;
            bf16x8 bfr = *(const bf16x8*)(winb + (long)col*DM + kg*8 + kk*32);
            acc[j] = __builtin_amdgcn_mfma_f32_16x16x32_bf16(af, bfr, acc[j], 0,0,0);
        }
    }
#pragma unroll
    for (int j = 0; j < 6; ++j){
        int col = nc0 + j*16 + lrow;
#pragma unroll
        for (int reg = 0; reg < 4; ++reg){
            int row = r0 + kg*4 + reg;
            float v = acc[j][reg];
            if (col < DI) xin[(long)row*DI + col] = v;
            else          zb[(long)row*DI + (col - DI)] = f2bf(v);
        }
    }
}

// ---- 2. depthwise conv + SiLU -> bf16 xcb ----
__global__ __launch_bounds__(256) void k_conv(const float* __restrict__ xin, const float* __restrict__ cwT,
                                              const float* __restrict__ cb, unsigned short* __restrict__ xcb){
    int g = blockIdx.x * 256 + threadIdx.x;
    int dq = g % 48; int d0 = dq * 4;
    int l = (g / 48) % LL;
    int b = g / (48 * LL);
    int h = l >> 6, wwi = l & 63;
    float4 acc = *(const float4*)(cb + d0);
    const float* base = xin + (long)b * LL * DI + d0;
#pragma unroll
    for (int dy = 0; dy < 3; ++dy){
        int hh = h + dy - 1;
        if (hh < 0 || hh >= 64) continue;
#pragma unroll
        for (int dx = 0; dx < 3; ++dx){
            int wx = wwi + dx - 1;
            if (wx < 0 || wx >= 64) continue;
            float4 xv = *(const float4*)(base + (long)(hh*64 + wx)*DI);
            float4 wv = *(const float4*)(cwT + (dy*3 + dx)*DI + d0);
            acc.x += xv.x*wv.x; acc.y += xv.y*wv.y; acc.z += xv.z*wv.z; acc.w += xv.w*wv.w;
        }
    }
    ushort4 o;
    o.x = f2bf(silu(acc.x)); o.y = f2bf(silu(acc.y));
    o.z = f2bf(silu(acc.z)); o.w = f2bf(silu(acc.w));
    *(ushort4*)(xcb + ((long)b*LL + l)*DI + d0) = o;
}

// ---- 3. x_proj+dt_proj spatial GEMM (A-tile shared by 4 directions) ----
#define XP 200
__global__ __launch_bounds__(512) void k_xdbl(const unsigned short* __restrict__ xcb, const unsigned short* __restrict__ wcomb,
                                              const float* __restrict__ dtb,
                                              unsigned short* __restrict__ delta, float* __restrict__ bc2){
    __shared__ unsigned short xsb[64*XP];
    int tid = threadIdx.x;
    int b    = blockIdx.x >> 6;
    int tile = blockIdx.x & 63;
    int p0 = tile * 64;
    for (int i = tid; i < 64*24; i += 512){
        int r = i / 24, q = i - r*24;
        uint4 v = *(const uint4*)(xcb + ((long)b*LL + p0 + r)*DI + q*8);
        *(uint4*)(&xsb[r*XP + q*8]) = v;
    }
    __syncthreads();

    int wv = tid >> 6, l = tid & 63;
    int k = wv & 3, ch = wv >> 2;
    int lrow = l & 15, kgrp = l >> 4;
    f32x4 acc[4][7];
#pragma unroll
    for (int rt = 0; rt < 4; ++rt)
#pragma unroll
        for (int j = 0; j < 7; ++j) acc[rt][j] = (f32x4){0,0,0,0};
    const unsigned short* wb = wcomb + (long)k*NCOMB*DI + ((long)ch*112 + lrow)*DI + kgrp*8;
#pragma unroll
    for (int ks = 0; ks < 6; ++ks){
        bf16x8 bfr[7];
#pragma unroll
        for (int nt = 0; nt < 7; ++nt)
            bfr[nt] = *(const bf16x8*)(wb + (long)nt*16*DI + ks*32);
        bf16x8 a[4];
#pragma unroll
        for (int rt = 0; rt < 4; ++rt)
            a[rt] = *(const bf16x8*)(&xsb[(rt*16 + lrow)*XP + kgrp*8 + ks*32]);
#pragma unroll
        for (int rt = 0; rt < 4; ++rt)
#pragma unroll
            for (int nt = 0; nt < 7; ++nt)
                acc[rt][nt] = __builtin_amdgcn_mfma_f32_16x16x32_bf16(a[rt], bfr[nt], acc[rt][nt], 0,0,0);
    }
    int bk = b*4 + k;
#pragma unroll
    for (int rt = 0; rt < 4; ++rt){
        long obase = (long)bk*LL + p0 + rt*16 + kgrp*4;
#pragma unroll
        for (int nt = 0; nt < 7; ++nt){
            int col = ch*112 + nt*16 + lrow;
            if (col < DI){
                float bias = dtb[k*DI + col];
#pragma unroll
                for (int reg = 0; reg < 4; ++reg){
                    float raw = acc[rt][nt][reg] + bias;
                    float sp = (raw > 15.f) ? raw : __logf(1.f + __expf(raw));
                    delta[(obase + reg)*DI + col] = f2bf(sp);
                }
            } else {
                int q = col - DI;
#pragma unroll
                for (int reg = 0; reg < 4; ++reg)
                    bc2[(obase + reg)*32 + q] = acc[rt][nt][reg];
            }
        }
    }
}

// ---- helper: one scanA step (fast path) ----
#define SCANA_STEP(DE,U,B0,B1,B2,B3)                                              \
    {                                                                             \
        float P[NS];                                                              \
        P[0] = __expf(-(DE));                                                     \
        P[1] = P[0]*P[0];                                                         \
        _Pragma("unroll")                                                         \
        for (int n = 2; n < NS; ++n) P[n] = P[(n-1)>>1] * P[n-1-((n-1)>>1)];      \
        float du = (DE) * (U);                                                    \
        S += (DE);                                                                \
        float bb[NS] = {B0.x,B0.y,B0.z,B0.w, B1.x,B1.y,B1.z,B1.w,                 \
                        B2.x,B2.y,B2.z,B2.w, B3.x,B3.y,B3.z,B3.w};                \
        _Pragma("unroll")                                                         \
        for (int n = 0; n < NS; ++n) h[n] = h[n]*P[n] + du*bb[n];                 \
    }

// ---- 4. scan pass A: depth-2 pipelined fast path ----
__global__ __launch_bounds__(192) void k_scanA(const unsigned short* __restrict__ delta, const float* __restrict__ bc2,
                                               const unsigned short* __restrict__ xcb, const float* __restrict__ alog,
                                               unsigned short* __restrict__ hloc, float* __restrict__ Ssum){
    int d = threadIdx.x;
    int bid = blockIdx.x;
    int c = bid & (NC-1); int bk = bid >> 7;
    int b = bk >> 2, k = bk & 3;
    float a[NS]; bool fast = true;
#pragma unroll
    for (int n = 0; n < NS; ++n){
        a[n] = -__expf(alog[(k*DI + d)*NS + n]);
        fast = fast && (fabsf(a[n] + (float)(n + 1)) < 1e-4f*(float)(n + 1));
    }
    int t0 = c * CL;
    int p0 = pos_of(k, t0);
    int st = (k == 0) ? 1 : (k == 1) ? 64 : (k == 2) ? -1 : -64;
    const unsigned short* dep = delta + ((long)bk*LL + p0)*DI + d;
    const float* bcp = bc2   + ((long)bk*LL + p0)*32;
    const unsigned short* up = xcb + ((long)b*LL + p0)*DI + d;
    long ustep = (long)st * DI;
    long bstep = (long)st * 32;
    float h[NS];
#pragma unroll
    for (int n = 0; n < NS; ++n) h[n] = 0.f;
    float S = 0.f;
    if (fast){
        // depth-2 pipeline: slots A (even i) and B (odd i)
        float deA = bf(dep), uA = bf(up);
        const float4* qa = (const float4*)bcp;
        float4 bA0 = qa[0], bA1 = qa[1], bA2 = qa[2], bA3 = qa[3];
        float deB = bf(dep + ustep), uB = bf(up + ustep);
        const float4* qb = (const float4*)(bcp + bstep);
        float4 bB0 = qb[0], bB1 = qb[1], bB2 = qb[2], bB3 = qb[3];
        dep += 2*ustep; up += 2*ustep; bcp += 2*bstep;
        for (int ii = 0; ii < CL; ii += 2){
            float deA_n = bf(dep), uA_n = bf(up);               // prefetch i+2 (tail in ws)
            const float4* qan = (const float4*)bcp;
            float4 bA0n = qan[0], bA1n = qan[1], bA2n = qan[2], bA3n = qan[3];
            dep += ustep; up += ustep; bcp += bstep;
            SCANA_STEP(deA, uA, bA0, bA1, bA2, bA3)
            float deB_n = bf(dep), uB_n = bf(up);               // prefetch i+3
            const float4* qbn = (const float4*)bcp;
            float4 bB0n = qbn[0], bB1n = qbn[1], bB2n = qbn[2], bB3n = qbn[3];
            dep += ustep; up += ustep; bcp += bstep;
            SCANA_STEP(deB, uB, bB0, bB1, bB2, bB3)
            deA = deA_n; uA = uA_n; bA0 = bA0n; bA1 = bA1n; bA2 = bA2n; bA3 = bA3n;
            deB = deB_n; uB = uB_n; bB0 = bB0n; bB1 = bB1n; bB2 = bB2n; bB3 = bB3n;
        }
    } else {
        for (int i = 0; i < CL; ++i){
            float de = bf(dep);
            float u  = bf(up);
            const float4* bq = (const float4*)bcp;
            float4 b0 = bq[0], b1 = bq[1], b2 = bq[2], b3 = bq[3];
            float du = de * u;
            S += de;
            float bb[NS] = {b0.x,b0.y,b0.z,b0.w, b1.x,b1.y,b1.z,b1.w,
                            b2.x,b2.y,b2.z,b2.w, b3.x,b3.y,b3.z,b3.w};
#pragma unroll
            for (int n = 0; n < NS; ++n){ float dA = __expf(de*a[n]); h[n] = h[n]*dA + du*bb[n]; }
            dep += ustep; up += ustep; bcp += bstep;
        }
    }
    long ho = (((long)bk*NC + c)*DI + d)*NS;
#pragma unroll
    for (int q = 0; q < 4; ++q){
        ushort4 o;
        o.x = f2bf(h[q*4]); o.y = f2bf(h[q*4+1]); o.z = f2bf(h[q*4+2]); o.w = f2bf(h[q*4+3]);
        *(ushort4*)(hloc + ho + q*4) = o;
    }
    Ssum[((long)bk*NC + c)*DI + d] = S;
}

// ---- 5. scan pass B: chunk combine (bf16 hloc), prefetched ----
__global__ __launch_bounds__(256) void k_scanB(unsigned short* __restrict__ hloc, const float* __restrict__ Ssum,
                                               const float* __restrict__ alog){
    int gid = blockIdx.x * 256 + threadIdx.x;
    int dn = gid % (DI*NS);
    int bk = gid / (DI*NS);
    int d = dn >> 4, n = dn & 15;
    int k = bk & 3;
    float a = -__expf(alog[(k*DI + d)*NS + n]);
    float h = 0.f;
    long o     = (long)bk * NC * DI * NS + dn;
    long sbase = (long)bk * NC * DI + d;
    float Sc  = Ssum[sbase];
    float tmp = bf(hloc + o);
    for (int c = 0; c < NC; ++c){
        long o_n = o + (long)DI*NS;
        float Sc_n  = Ssum[sbase + (long)(c+1)*DI];   // tail over-read stays in ws
        float tmp_n = bf(hloc + o_n);
        float P = __expf(a * Sc);
        hloc[o] = f2bf(h);
        h = h * P + tmp;
        o = o_n; Sc = Sc_n; tmp = tmp_n;
    }
}

// ---- helper: one scanC step (fast path) ----
#define SCANC_STEP(DE,U,B0,B1,B2,B3,C0,C1,C2,C3)                                  \
    {                                                                             \
        float P[NS];                                                              \
        P[0] = __expf(-(DE));                                                     \
        P[1] = P[0]*P[0];                                                         \
        _Pragma("unroll")                                                         \
        for (int n = 2; n < NS; ++n) P[n] = P[(n-1)>>1] * P[n-1-((n-1)>>1)];      \
        float du = (DE) * (U);                                                    \
        float bb[NS] = {B0.x,B0.y,B0.z,B0.w, B1.x,B1.y,B1.z,B1.w,                 \
                        B2.x,B2.y,B2.z,B2.w, B3.x,B3.y,B3.z,B3.w};                \
        float cc[NS] = {C0.x,C0.y,C0.z,C0.w, C1.x,C1.y,C1.z,C1.w,                 \
                        C2.x,C2.y,C2.z,C2.w, C3.x,C3.y,C3.z,C3.w};                \
        float y = 0.f;                                                            \
        _Pragma("unroll")                                                         \
        for (int n = 0; n < NS; ++n){ h[n] = h[n]*P[n] + du*bb[n]; y += h[n]*cc[n]; } \
        *yp = f2bf(y);                                                            \
        yp += ustep;                                                              \
    }

// ---- 6. scan pass C: depth-2 pipelined fast path; bf16 y ----
__global__ __launch_bounds__(192) void k_scanC(const unsigned short* __restrict__ delta, const float* __restrict__ bc2,
                                               const unsigned short* __restrict__ xcb, const float* __restrict__ alog,
                                               const unsigned short* __restrict__ hloc, unsigned short* __restrict__ ys){
    int d = threadIdx.x;
    int bid = blockIdx.x;
    int c = bid & (NC-1); int bk = bid >> 7;
    int b = bk >> 2, k = bk & 3;
    float a[NS]; bool fast = true;
#pragma unroll
    for (int n = 0; n < NS; ++n){
        a[n] = -__expf(alog[(k*DI + d)*NS + n]);
        fast = fast && (fabsf(a[n] + (float)(n + 1)) < 1e-4f*(float)(n + 1));
    }
    int t0 = c * CL;
    int p0 = pos_of(k, t0);
    int st = (k == 0) ? 1 : (k == 1) ? 64 : (k == 2) ? -1 : -64;
    const unsigned short* dep = delta + ((long)bk*LL + p0)*DI + d;
    const float* bcp = bc2   + ((long)bk*LL + p0)*32;
    const unsigned short* up = xcb + ((long)b*LL + p0)*DI + d;
    unsigned short* yp = ys + ((long)bk*LL + p0)*DI + d;
    long ustep = (long)st * DI;
    long bstep = (long)st * 32;
    long ho = (((long)bk*NC + c)*DI + d)*NS;
    float h[NS];
#pragma unroll
    for (int n = 0; n < NS; ++n) h[n] = bf(hloc + ho + n);
    if (fast){
        float deA = bf(dep), uA = bf(up);
        const float4* qa = (const float4*)bcp;
        float4 bA0 = qa[0], bA1 = qa[1], bA2 = qa[2], bA3 = qa[3];
        float4 cA0 = qa[4], cA1 = qa[5], cA2 = qa[6], cA3 = qa[7];
        float deB = bf(dep + ustep), uB = bf(up + ustep);
        const float4* qb = (const float4*)(bcp + bstep);
        float4 bB0 = qb[0], bB1 = qb[1], bB2 = qb[2], bB3 = qb[3];
        float4 cB0 = qb[4], cB1 = qb[5], cB2 = qb[6], cB3 = qb[7];
        dep += 2*ustep; up += 2*ustep; bcp += 2*bstep;
        for (int ii = 0; ii < CL; ii += 2){
            float deA_n = bf(dep), uA_n = bf(up);
            const float4* qan = (const float4*)bcp;
            float4 bA0n = qan[0], bA1n = qan[1], bA2n = qan[2], bA3n = qan[3];
            float4 cA0n = qan[4], cA1n = qan[5], cA2n = qan[6], cA3n = qan[7];
            dep += ustep; up += ustep; bcp += bstep;
            SCANC_STEP(deA, uA, bA0, bA1, bA2, bA3, cA0, cA1, cA2, cA3)
            float deB_n = bf(dep), uB_n = bf(up);
            const float4* qbn = (const float4*)bcp;
            float4 bB0n = qbn[0], bB1n = qbn[1], bB2n = qbn[2], bB3n = qbn[3];
            float4 cB0n = qbn[4], cB1n = qbn[5], cB2n = qbn[6], cB3n = qbn[7];
            dep += ustep; up += ustep; bcp += bstep;
            SCANC_STEP(deB, uB, bB0, bB1, bB2, bB3, cB0, cB1, cB2, cB3)
            deA = deA_n; uA = uA_n;
            bA0 = bA0n; bA1 = bA1n; bA2 = bA2n; bA3 = bA3n;
            cA0 = cA0n; cA1 = cA1n; cA2 = cA2n; cA3 = cA3n;
            deB = deB_n; uB = uB_n;
            bB0 = bB0n; bB1 = bB1n; bB2 = bB2n; bB3 = bB3n;
            cB0 = cB0n; cB1 = cB1n; cB2 = cB2n; cB3 = cB3n;
        }
    } else {
        for (int i = 0; i < CL; ++i){
            float de = bf(dep);
            float u  = bf(up);
            const float4* bq = (const float4*)bcp;
            float4 b0 = bq[0], b1 = bq[1], b2 = bq[2], b3 = bq[3];
            float4 c0 = bq[4], c1 = bq[5], c2 = bq[6], c3 = bq[7];
            float du = de * u;
            float bb[NS] = {b0.x,b0.y,b0.z,b0.w, b1.x,b1.y,b1.z,b1.w,
                            b2.x,b2.y,b2.z,b2.w, b3.x,b3.y,b3.z,b3.w};
            float cc[NS] = {c0.x,c0.y,c0.z,c0.w, c1.x,c1.y,c1.z,c1.w,
                            c2.x,c2.y,c2.z,c2.w, c3.x,c3.y,c3.z,c3.w};
            float y = 0.f;
#pragma unroll
            for (int n = 0; n < NS; ++n){ float dA = __expf(de*a[n]); h[n] = h[n]*dA + du*bb[n]; y += h[n]*cc[n]; }
            *yp = f2bf(y);
            dep += ustep; up += ustep; yp += ustep; bcp += bstep;
        }
    }
}

// ---- 7. merge + LN + gate + out_proj: wave-per-pixel LN, MFMA out_proj ----
__global__ __launch_bounds__(256) void k_fuse(const unsigned short* __restrict__ ys, const unsigned short* __restrict__ xcb,
                                              const unsigned short* __restrict__ zb, const float* __restrict__ Dsk,
                                              const float* __restrict__ lnw, const float* __restrict__ lnb,
                                              const unsigned short* __restrict__ woutb, float* __restrict__ out){
    __shared__ unsigned short gt[32*200];
    int tid = threadIdx.x;
    int wv = tid >> 6, l = tid & 63;
    int b  = blockIdx.x / (LL/32);
    int p0 = (blockIdx.x % (LL/32)) * 32;
    float sumD[3], lw[3], lb[3];
#pragma unroll
    for (int q = 0; q < 3; ++q){
        int d = l + q*64;
        sumD[q] = Dsk[d] + Dsk[DI + d] + Dsk[2*DI + d] + Dsk[3*DI + d];
        lw[q] = lnw[d]; lb[q] = lnb[d];
    }
    for (int pass = 0; pass < 8; ++pass){
        int pl = wv*8 + pass;
        int p = p0 + pl;
        long base = (long)b*LL + p;
        float yv[3], zv[3];
        float s = 0.f, sq = 0.f;
#pragma unroll
        for (int q = 0; q < 3; ++q){
            int d = l + q*64;
            long yo = ((long)(b*4)*LL + p)*DI + d;
            float y = bf(ys + yo) + bf(ys + yo + (long)LL*DI)
                    + bf(ys + yo + 2L*LL*DI) + bf(ys + yo + 3L*LL*DI);
            y += bf(xcb + base*DI + d) * sumD[q];
            zv[q] = bf(zb + base*DI + d);
            yv[q] = y; s += y; sq += y*y;
        }
#pragma unroll
        for (int m = 32; m > 0; m >>= 1){ s += __shfl_xor(s, m, 64); sq += __shfl_xor(sq, m, 64); }
        float mu = s / DI, var = sq / DI - mu*mu;
        float rs = rsqrtf(var + 1e-5f);
#pragma unroll
        for (int q = 0; q < 3; ++q){
            int d = l + q*64;
            float yn = (yv[q] - mu)*rs*lw[q] + lb[q];
            gt[pl*200 + d] = f2bf(yn * silu(zv[q]));
        }
    }
    __syncthreads();
    int lrow = l & 15, kg = l >> 4;
    int rt = wv & 1, cp = wv >> 1;
    f32x4 acc[3];
#pragma unroll
    for (int j = 0; j < 3; ++j) acc[j] = (f32x4){0,0,0,0};
    const unsigned short* arow = &gt[(rt*16 + lrow)*200 + kg*8];
    const unsigned short* wbase = woutb + ((long)cp*48 + lrow)*DI + kg*8;
#pragma unroll
    for (int ks = 0; ks < 6; ++ks){
        bf16x8 af = *(const bf16x8*)(arow + ks*32);
#pragma unroll
        for (int nt = 0; nt < 3; ++nt){
            bf16x8 bfr = *(const bf16x8*)(wbase + (long)nt*16*DI + ks*32);
            acc[nt] = __builtin_amdgcn_mfma_f32_16x16x32_bf16(af, bfr, acc[nt], 0,0,0);
        }
    }
#pragma unroll
    for (int nt = 0; nt < 3; ++nt){
        int m = cp*48 + nt*16 + lrow;
#pragma unroll
        for (int reg = 0; reg < 4; ++reg){
            int pl = rt*16 + kg*4 + reg;
            out[((long)b*LL + p0 + pl)*DM + m] = acc[nt][reg];
        }
    }
}

extern "C" void kernel_launch(void* const* d_in, const int* in_sizes, int n_in,
                              void* d_out, int out_size, void* d_ws, size_t ws_size,
                              hipStream_t stream){
    (void)in_sizes; (void)n_in; (void)out_size; (void)ws_size;
    const float* x    = (const float*)d_in[0];
    const float* win  = (const float*)d_in[1];
    const float* cw   = (const float*)d_in[2];
    const float* cb   = (const float*)d_in[3];
    const float* xpw  = (const float*)d_in[4];
    const float* dtw  = (const float*)d_in[5];
    const float* dtb  = (const float*)d_in[6];
    const float* alog = (const float*)d_in[7];
    const float* ds   = (const float*)d_in[8];
    const float* lnw  = (const float*)d_in[9];
    const float* lnb  = (const float*)d_in[10];
    const float* wout = (const float*)d_in[11];

    float* ws    = (float*)d_ws;
    float* xin   = ws + OFF_XIN;
    unsigned short* zb    = (unsigned short*)(ws + OFF_Z);
    unsigned short* xcb   = (unsigned short*)(ws + OFF_XC);
    unsigned short* delta = (unsigned short*)(ws + OFF_DELTA);
    unsigned short* hloc  = (unsigned short*)(ws + OFF_HLOC);
    float* bc2   = ws + OFF_BC;
    unsigned short* ysb = (unsigned short*)(ws + OFF_YS);
    float* Ssum  = ws + OFF_S;
    unsigned short* winb  = (unsigned short*)(ws + OFF_WB);
    float* cwT   = ws + OFF_CWT;
    unsigned short* wcomb = (unsigned short*)(ws + OFF_WC);
    unsigned short* woutb = (unsigned short*)(ws + OFF_WO);

    k_prep  <<<dim3(672),  dim3(256), 0, stream>>>(win, cw, xpw, dtw, wout, winb, cwT, wcomb, woutb);
    k_inproj<<<dim3(1024), dim3(256), 0, stream>>>(x, winb, xin, zb);
    k_conv  <<<dim3(3072), dim3(256), 0, stream>>>(xin, cwT, cb, xcb);
    k_xdbl  <<<dim3(256),  dim3(512), 0, stream>>>(xcb, wcomb, dtb, delta, bc2);
    k_scanA <<<dim3(2048), dim3(192), 0, stream>>>(delta, bc2, xcb, alog, hloc, Ssum);
    k_scanB <<<dim3(192),  dim3(256), 0, stream>>>(hloc, Ssum, alog);
    k_scanC <<<dim3(2048), dim3(192), 0, stream>>>(delta, bc2, xcb, alog, hloc, ysb);
    k_fuse  <<<dim3(512),  dim3(256), 0, stream>>>(ysb, xcb, zb, ds, lnw, lnb, woutb,
                                                   (float*)d_out);
}

// Round 20
// 142.879 us; speedup vs baseline: 1.0458x; 1.0458x over previous
//
#include <hip/hip_runtime.h>
#include <hip/hip_bf16.h>

#define DEV static __device__ __forceinline__

DEV float silu(float x){ return x / (1.f + __expf(-x)); }

typedef __attribute__((ext_vector_type(8))) short bf16x8;
typedef __attribute__((ext_vector_type(4))) float f32x4;

DEV unsigned short f2bf(float f){
    unsigned u = __float_as_uint(f);
    u += 0x7FFF + ((u >> 16) & 1);      // RNE
    return (unsigned short)(u >> 16);
}
DEV float bf(const unsigned short* p){ return __uint_as_float(((unsigned)(*p)) << 16); }

// ---- problem sizes ----
#define BB 4
#define LL 4096          // H*W, H=W=64
#define DM 96
#define DI 192
#define NS 16
#define KK 4
#define RR 6
#define C38 38
#define NC 128           // chunks
#define CL 32            // chunk length
#define NCOMB 224        // combined x_proj/dt_proj rows: 192 delta + 32 B/C

// ---- workspace layout (float offsets) ----
#define OFF_XIN   0
#define OFF_Z     (OFF_XIN + BB*LL*DI)
#define OFF_XC    (OFF_Z + BB*LL*DI)
#define OFF_DELTA (OFF_XC + BB*LL*DI)          // u16 data in first half of slot; SPATIAL order
#define OFF_HLOC  (OFF_DELTA + BB*KK*LL*DI/2)  // f32, upper half of delta slot (exact fit)
#define OFF_BC    (OFF_DELTA + BB*KK*LL*DI)    // f32, SPATIAL order
#define OFF_YS    (OFF_BC + BB*KK*LL*32)       // u16 region (uses half the slot)
#define OFF_S     (OFF_YS + BB*KK*LL*DI)
#define OFF_WB    (OFF_S + BB*KK*NC*DI)         // bf16 in_proj weights
#define OFF_CWT   (OFF_WB + 18432)              // f32 transposed conv weights
#define OFF_WC    (OFF_CWT + 1728)              // bf16 combined x/dt proj weights
#define OFF_WO    (OFF_WC + 86016)              // bf16 out_proj weights

DEV int pos_of(int k, int t){
    int pr = ((t & 63) << 6) | (t >> 6);
    int p  = (k & 1) ? pr : t;
    if (k & 2) p = LL - 1 - p;
    return p;
}

// ---- 0. prep ----
__global__ __launch_bounds__(256) void k_prep(const float* __restrict__ win, const float* __restrict__ cw,
                                              const float* __restrict__ xpw, const float* __restrict__ dtw,
                                              const float* __restrict__ wout,
                                              unsigned short* __restrict__ winb, float* __restrict__ cwT,
                                              unsigned short* __restrict__ wcomb, unsigned short* __restrict__ woutb){
    int i = blockIdx.x * 256 + threadIdx.x;
    if (i < 384*DM) winb[i] = f2bf(win[i]);
    if (i < 9*DI){ int tap = i / DI, d = i - tap*DI; cwT[i] = cw[d*9 + tap]; }
    if (i < DM*DI) woutb[i] = f2bf(wout[i]);
    if (i < KK*NCOMB*DI){
        int kk = i % DI; int j = (i / DI) % NCOMB; int k = i / (DI*NCOMB);
        float v;
        if (j < DI){
            v = 0.f;
            const float* dtwp = dtw + ((long)k*DI + j)*RR;
            const float* xp   = xpw + (long)k*C38*DI + kk;
#pragma unroll
            for (int r = 0; r < RR; ++r) v += dtwp[r] * xp[(long)r*DI];
        } else {
            v = xpw[(long)k*C38*DI + (long)(6 + j - DI)*DI + kk];
        }
        wcomb[i] = f2bf(v);
    }
}

// ---- 1. in_proj: bf16 MFMA GEMM ----
__global__ __launch_bounds__(256) void k_inproj(const float* __restrict__ x, const unsigned short* __restrict__ winb,
                                                float* __restrict__ xin, float* __restrict__ z){
    __shared__ unsigned short xsb[16*104];
    int tid = threadIdx.x;
    int r0 = blockIdx.x * 16;
    const float* xrow = x + (long)r0 * DM;
    for (int i = tid; i < 16*DM; i += 256){
        int r = i / DM, d = i - r*DM;
        xsb[r*104 + d] = f2bf(xrow[i]);
    }
    __syncthreads();
    int wv = tid >> 6, l = tid & 63;
    int lrow = l & 15, kg = l >> 4;
    int nc0 = wv * 96;
    f32x4 acc[6];
#pragma unroll
    for (int j = 0; j < 6; ++j) acc[j] = (f32x4){0,0,0,0};
    const unsigned short* arow = &xsb[lrow*104 + kg*8];
#pragma unroll
    for (int kk = 0; kk < 3; ++kk){
        bf16x8 af = *(const bf16x8*)(arow + kk*32);
#pragma unroll
        for (int j = 0; j < 6; ++j){
            int col = nc0 + j*16 + lrow;
            bf16x8 bfr = *(const bf16x8*)(winb + (long)col*DM + kg*8 + kk*32);
            acc[j] = __builtin_amdgcn_mfma_f32_16x16x32_bf16(af, bfr, acc[j], 0,0,0);
        }
    }
#pragma unroll
    for (int j = 0; j < 6; ++j){
        int col = nc0 + j*16 + lrow;
#pragma unroll
        for (int reg = 0; reg < 4; ++reg){
            int row = r0 + kg*4 + reg;
            float v = acc[j][reg];
            if (col < DI) xin[(long)row*DI + col] = v;
            else          z[(long)row*DI + (col - DI)] = v;
        }
    }
}

// ---- 2. depthwise conv + SiLU, float4 ----
__global__ __launch_bounds__(256) void k_conv(const float* __restrict__ xin, const float* __restrict__ cwT,
                                              const float* __restrict__ cb, float* __restrict__ xc){
    int g = blockIdx.x * 256 + threadIdx.x;
    int dq = g % 48; int d0 = dq * 4;
    int l = (g / 48) % LL;
    int b = g / (48 * LL);
    int h = l >> 6, wwi = l & 63;
    float4 acc = *(const float4*)(cb + d0);
    const float* base = xin + (long)b * LL * DI + d0;
#pragma unroll
    for (int dy = 0; dy < 3; ++dy){
        int hh = h + dy - 1;
        if (hh < 0 || hh >= 64) continue;
#pragma unroll
        for (int dx = 0; dx < 3; ++dx){
            int wx = wwi + dx - 1;
            if (wx < 0 || wx >= 64) continue;
            float4 xv = *(const float4*)(base + (long)(hh*64 + wx)*DI);
            float4 wv = *(const float4*)(cwT + (dy*3 + dx)*DI + d0);
            acc.x += xv.x*wv.x; acc.y += xv.y*wv.y; acc.z += xv.z*wv.z; acc.w += xv.w*wv.w;
        }
    }
    float4 o;
    o.x = silu(acc.x); o.y = silu(acc.y); o.z = silu(acc.z); o.w = silu(acc.w);
    *(float4*)(xc + ((long)b*LL + l)*DI + d0) = o;
}

// ---- 3. x_proj+dt_proj in SPATIAL order: one A-tile serves all 4 directions ----
#define XP 200
__global__ __launch_bounds__(512) void k_xdbl(const float* __restrict__ xc, const unsigned short* __restrict__ wcomb,
                                              const float* __restrict__ dtb,
                                              unsigned short* __restrict__ delta, float* __restrict__ bc2){
    __shared__ unsigned short xsb[64*XP];
    int tid = threadIdx.x;
    int b    = blockIdx.x >> 6;
    int tile = blockIdx.x & 63;
    int p0 = tile * 64;
    for (int i = tid; i < 64*48; i += 512){
        int r = i / 48, q = i - r*48;
        float4 v = *(const float4*)(xc + ((long)b*LL + p0 + r)*DI + q*4);
        ushort4 o;
        o.x = f2bf(v.x); o.y = f2bf(v.y); o.z = f2bf(v.z); o.w = f2bf(v.w);
        *(ushort4*)(&xsb[r*XP + q*4]) = o;
    }
    __syncthreads();

    int wv = tid >> 6, l = tid & 63;
    int k = wv & 3, ch = wv >> 2;
    int lrow = l & 15, kgrp = l >> 4;
    f32x4 acc[4][7];
#pragma unroll
    for (int rt = 0; rt < 4; ++rt)
#pragma unroll
        for (int j = 0; j < 7; ++j) acc[rt][j] = (f32x4){0,0,0,0};
    const unsigned short* wb = wcomb + (long)k*NCOMB*DI + ((long)ch*112 + lrow)*DI + kgrp*8;
#pragma unroll
    for (int ks = 0; ks < 6; ++ks){
        bf16x8 bfr[7];
#pragma unroll
        for (int nt = 0; nt < 7; ++nt)
            bfr[nt] = *(const bf16x8*)(wb + (long)nt*16*DI + ks*32);
        bf16x8 a[4];
#pragma unroll
        for (int rt = 0; rt < 4; ++rt)
            a[rt] = *(const bf16x8*)(&xsb[(rt*16 + lrow)*XP + kgrp*8 + ks*32]);
#pragma unroll
        for (int rt = 0; rt < 4; ++rt)
#pragma unroll
            for (int nt = 0; nt < 7; ++nt)
                acc[rt][nt] = __builtin_amdgcn_mfma_f32_16x16x32_bf16(a[rt], bfr[nt], acc[rt][nt], 0,0,0);
    }
    int bk = b*4 + k;
#pragma unroll
    for (int rt = 0; rt < 4; ++rt){
        long obase = (long)bk*LL + p0 + rt*16 + kgrp*4;
#pragma unroll
        for (int nt = 0; nt < 7; ++nt){
            int col = ch*112 + nt*16 + lrow;
            if (col < DI){
                float bias = dtb[k*DI + col];
#pragma unroll
                for (int reg = 0; reg < 4; ++reg){
                    float raw = acc[rt][nt][reg] + bias;
                    float sp = (raw > 15.f) ? raw : __logf(1.f + __expf(raw));
                    delta[(obase + reg)*DI + col] = f2bf(sp);
                }
            } else {
                int q = col - DI;
#pragma unroll
                for (int reg = 0; reg < 4; ++reg)
                    bc2[(obase + reg)*32 + q] = acc[rt][nt][reg];
            }
        }
    }
}

// ---- 4. scan pass A: NC=128 chunks; spatial reads; 16 n-states/thread; prefetch ----
__global__ __launch_bounds__(192) void k_scanA(const unsigned short* __restrict__ delta, const float* __restrict__ bc2,
                                               const float* __restrict__ xc, const float* __restrict__ alog,
                                               float* __restrict__ hloc, float* __restrict__ Ssum){
    int d = threadIdx.x;
    int bid = blockIdx.x;
    int c = bid & (NC-1); int bk = bid >> 7;
    int b = bk >> 2, k = bk & 3;
    float a[NS]; bool fast = true;
#pragma unroll
    for (int n = 0; n < NS; ++n){
        a[n] = -__expf(alog[(k*DI + d)*NS + n]);
        fast = fast && (fabsf(a[n] + (float)(n + 1)) < 1e-4f*(float)(n + 1));
    }
    int t0 = c * CL;
    int p0 = pos_of(k, t0);
    int st = (k == 0) ? 1 : (k == 1) ? 64 : (k == 2) ? -1 : -64;
    const unsigned short* dep = delta + ((long)bk*LL + p0)*DI + d;
    const float* bcp = bc2   + ((long)bk*LL + p0)*32;   // block-uniform
    const float* up  = xc + ((long)b*LL + p0)*DI + d;
    long ustep = (long)st * DI;
    long bstep = (long)st * 32;
    float h[NS];
#pragma unroll
    for (int n = 0; n < NS; ++n) h[n] = 0.f;
    float S = 0.f;
    if (fast){
        float de = bf(dep), u = *up;
        const float4* bq = (const float4*)bcp;
        float4 b0 = bq[0], b1 = bq[1], b2 = bq[2], b3 = bq[3];
        for (int i = 0; i < CL; ++i){
            dep += ustep; up += ustep; bcp += bstep;
            float de_n = bf(dep);                   // tail over-read stays in ws
            float u_n  = *up;
            const float4* bqn = (const float4*)bcp;
            float4 b0n = bqn[0], b1n = bqn[1], b2n = bqn[2], b3n = bqn[3];
            float P[NS];
            P[0] = __expf(-de);
            P[1] = P[0]*P[0];
#pragma unroll
            for (int n = 2; n < NS; ++n) P[n] = P[(n-1)>>1] * P[n-1-((n-1)>>1)];
            float du = de * u;
            S += de;
            float bb[NS] = {b0.x,b0.y,b0.z,b0.w, b1.x,b1.y,b1.z,b1.w,
                            b2.x,b2.y,b2.z,b2.w, b3.x,b3.y,b3.z,b3.w};
#pragma unroll
            for (int n = 0; n < NS; ++n) h[n] = h[n]*P[n] + du*bb[n];
            de = de_n; u = u_n; b0 = b0n; b1 = b1n; b2 = b2n; b3 = b3n;
        }
    } else {
        for (int i = 0; i < CL; ++i){
            float de = bf(dep);
            float u  = *up;
            const float4* bq = (const float4*)bcp;
            float4 b0 = bq[0], b1 = bq[1], b2 = bq[2], b3 = bq[3];
            float du = de * u;
            S += de;
            float bb[NS] = {b0.x,b0.y,b0.z,b0.w, b1.x,b1.y,b1.z,b1.w,
                            b2.x,b2.y,b2.z,b2.w, b3.x,b3.y,b3.z,b3.w};
#pragma unroll
            for (int n = 0; n < NS; ++n){ float dA = __expf(de*a[n]); h[n] = h[n]*dA + du*bb[n]; }
            dep += ustep; up += ustep; bcp += bstep;
        }
    }
    long ho = (((long)bk*NC + c)*DI + d)*NS;
#pragma unroll
    for (int q = 0; q < 4; ++q)
        *(float4*)(hloc + ho + q*4) = make_float4(h[q*4],h[q*4+1],h[q*4+2],h[q*4+3]);
    Ssum[((long)bk*NC + c)*DI + d] = S;
}

// ---- 5. scan pass B: chunk combine (NC=128), prefetched ----
__global__ __launch_bounds__(256) void k_scanB(float* __restrict__ hloc, const float* __restrict__ Ssum,
                                               const float* __restrict__ alog){
    int gid = blockIdx.x * 256 + threadIdx.x;
    int dn = gid % (DI*NS);
    int bk = gid / (DI*NS);
    int d = dn >> 4, n = dn & 15;
    int k = bk & 3;
    float a = -__expf(alog[(k*DI + d)*NS + n]);
    float h = 0.f;
    long o     = (long)bk * NC * DI * NS + dn;
    long sbase = (long)bk * NC * DI + d;
    float Sc  = Ssum[sbase];
    float tmp = hloc[o];
    for (int c = 0; c < NC; ++c){
        long o_n = o + (long)DI*NS;
        float Sc_n  = Ssum[sbase + (long)(c+1)*DI];   // tail over-read stays in ws
        float tmp_n = hloc[o_n];
        float P = __expf(a * Sc);
        hloc[o] = h;
        h = h * P + tmp;
        o = o_n; Sc = Sc_n; tmp = tmp_n;
    }
}

// ---- 6. scan pass C: NC=128; spatial reads; replay; bf16 y store ----
__global__ __launch_bounds__(192) void k_scanC(const unsigned short* __restrict__ delta, const float* __restrict__ bc2,
                                               const float* __restrict__ xc, const float* __restrict__ alog,
                                               const float* __restrict__ hloc, unsigned short* __restrict__ ys){
    int d = threadIdx.x;
    int bid = blockIdx.x;
    int c = bid & (NC-1); int bk = bid >> 7;
    int b = bk >> 2, k = bk & 3;
    float a[NS]; bool fast = true;
#pragma unroll
    for (int n = 0; n < NS; ++n){
        a[n] = -__expf(alog[(k*DI + d)*NS + n]);
        fast = fast && (fabsf(a[n] + (float)(n + 1)) < 1e-4f*(float)(n + 1));
    }
    int t0 = c * CL;
    int p0 = pos_of(k, t0);
    int st = (k == 0) ? 1 : (k == 1) ? 64 : (k == 2) ? -1 : -64;
    const unsigned short* dep = delta + ((long)bk*LL + p0)*DI + d;
    const float* bcp = bc2   + ((long)bk*LL + p0)*32;   // block-uniform
    const float* up  = xc + ((long)b*LL + p0)*DI + d;
    unsigned short* yp = ys + ((long)bk*LL + p0)*DI + d;
    long ustep = (long)st * DI;
    long bstep = (long)st * 32;
    long ho = (((long)bk*NC + c)*DI + d)*NS;
    float h[NS];
#pragma unroll
    for (int q = 0; q < 4; ++q){
        float4 hv = *(const float4*)(hloc + ho + q*4);
        h[q*4] = hv.x; h[q*4+1] = hv.y; h[q*4+2] = hv.z; h[q*4+3] = hv.w;
    }
    if (fast){
        float de = bf(dep), u = *up;
        const float4* bq = (const float4*)bcp;
        float4 b0 = bq[0], b1 = bq[1], b2 = bq[2], b3 = bq[3];
        float4 c0 = bq[4], c1 = bq[5], c2 = bq[6], c3 = bq[7];
        for (int i = 0; i < CL; ++i){
            dep += ustep; up += ustep; bcp += bstep;
            float de_n = bf(dep);
            float u_n  = *up;
            const float4* bqn = (const float4*)bcp;
            float4 b0n = bqn[0], b1n = bqn[1], b2n = bqn[2], b3n = bqn[3];
            float4 c0n = bqn[4], c1n = bqn[5], c2n = bqn[6], c3n = bqn[7];
            float P[NS];
            P[0] = __expf(-de);
            P[1] = P[0]*P[0];
#pragma unroll
            for (int n = 2; n < NS; ++n) P[n] = P[(n-1)>>1] * P[n-1-((n-1)>>1)];
            float du = de * u;
            float bb[NS] = {b0.x,b0.y,b0.z,b0.w, b1.x,b1.y,b1.z,b1.w,
                            b2.x,b2.y,b2.z,b2.w, b3.x,b3.y,b3.z,b3.w};
            float cc[NS] = {c0.x,c0.y,c0.z,c0.w, c1.x,c1.y,c1.z,c1.w,
                            c2.x,c2.y,c2.z,c2.w, c3.x,c3.y,c3.z,c3.w};
            float y = 0.f;
#pragma unroll
            for (int n = 0; n < NS; ++n){ h[n] = h[n]*P[n] + du*bb[n]; y += h[n]*cc[n]; }
            *yp = f2bf(y);
            yp += ustep;
            de = de_n; u = u_n;
            b0 = b0n; b1 = b1n; b2 = b2n; b3 = b3n;
            c0 = c0n; c1 = c1n; c2 = c2n; c3 = c3n;
        }
    } else {
        for (int i = 0; i < CL; ++i){
            float de = bf(dep);
            float u  = *up;
            const float4* bq = (const float4*)bcp;
            float4 b0 = bq[0], b1 = bq[1], b2 = bq[2], b3 = bq[3];
            float4 c0 = bq[4], c1 = bq[5], c2 = bq[6], c3 = bq[7];
            float du = de * u;
            float bb[NS] = {b0.x,b0.y,b0.z,b0.w, b1.x,b1.y,b1.z,b1.w,
                            b2.x,b2.y,b2.z,b2.w, b3.x,b3.y,b3.z,b3.w};
            float cc[NS] = {c0.x,c0.y,c0.z,c0.w, c1.x,c1.y,c1.z,c1.w,
                            c2.x,c2.y,c2.z,c2.w, c3.x,c3.y,c3.z,c3.w};
            float y = 0.f;
#pragma unroll
            for (int n = 0; n < NS; ++n){ float dA = __expf(de*a[n]); h[n] = h[n]*dA + du*bb[n]; y += h[n]*cc[n]; }
            *yp = f2bf(y);
            dep += ustep; up += ustep; yp += ustep; bcp += bstep;
        }
    }
}

// ---- 7. merge + LN + gate + out_proj: 16 px/block (2x occupancy), MFMA out_proj ----
__global__ __launch_bounds__(256) void k_fuse(const unsigned short* __restrict__ ys, const float* __restrict__ xc,
                                              const float* __restrict__ z, const float* __restrict__ Dsk,
                                              const float* __restrict__ lnw, const float* __restrict__ lnb,
                                              const unsigned short* __restrict__ woutb, float* __restrict__ out){
    __shared__ unsigned short gt[16*200];
    int tid = threadIdx.x;
    int wv = tid >> 6, l = tid & 63;
    int b  = blockIdx.x >> 8;             // 1024 blocks: 4 b x 256 tiles
    int p0 = (blockIdx.x & 255) * 16;
    float sumD[3], lw[3], lb[3];
#pragma unroll
    for (int q = 0; q < 3; ++q){
        int d = l + q*64;
        sumD[q] = Dsk[d] + Dsk[DI + d] + Dsk[2*DI + d] + Dsk[3*DI + d];
        lw[q] = lnw[d]; lb[q] = lnb[d];
    }
    for (int pass = 0; pass < 4; ++pass){
        int pl = wv*4 + pass;
        int p = p0 + pl;
        long base = (long)b*LL + p;
        float yv[3], zv[3];
        float s = 0.f, sq = 0.f;
#pragma unroll
        for (int q = 0; q < 3; ++q){
            int d = l + q*64;
            long yo = ((long)(b*4)*LL + p)*DI + d;
            float y = bf(ys + yo) + bf(ys + yo + (long)LL*DI)
                    + bf(ys + yo + 2L*LL*DI) + bf(ys + yo + 3L*LL*DI);
            y += xc[base*DI + d] * sumD[q];
            zv[q] = z[base*DI + d];
            yv[q] = y; s += y; sq += y*y;
        }
#pragma unroll
        for (int m = 32; m > 0; m >>= 1){ s += __shfl_xor(s, m, 64); sq += __shfl_xor(sq, m, 64); }
        float mu = s / DI, var = sq / DI - mu*mu;
        float rs = rsqrtf(var + 1e-5f);
#pragma unroll
        for (int q = 0; q < 3; ++q){
            int d = l + q*64;
            float yn = (yv[q] - mu)*rs*lw[q] + lb[q];
            gt[pl*200 + d] = f2bf(yn * silu(zv[q]));
        }
    }
    __syncthreads();
    // out_proj: out(16x96) = g(16x192) @ woutb^T(96x192); waves 0-1 (48 cols each)
    if (wv < 2){
        int lrow = l & 15, kg = l >> 4;
        int cp = wv;
        f32x4 acc[3];
#pragma unroll
        for (int j = 0; j < 3; ++j) acc[j] = (f32x4){0,0,0,0};
        const unsigned short* arow = &gt[lrow*200 + kg*8];
        const unsigned short* wbase = woutb + ((long)cp*48 + lrow)*DI + kg*8;
#pragma unroll
        for (int ks = 0; ks < 6; ++ks){
            bf16x8 af = *(const bf16x8*)(arow + ks*32);
#pragma unroll
            for (int nt = 0; nt < 3; ++nt){
                bf16x8 bfr = *(const bf16x8*)(wbase + (long)nt*16*DI + ks*32);
                acc[nt] = __builtin_amdgcn_mfma_f32_16x16x32_bf16(af, bfr, acc[nt], 0,0,0);
            }
        }
#pragma unroll
        for (int nt = 0; nt < 3; ++nt){
            int m = cp*48 + nt*16 + lrow;
#pragma unroll
            for (int reg = 0; reg < 4; ++reg){
                int pl = kg*4 + reg;
                out[((long)b*LL + p0 + pl)*DM + m] = acc[nt][reg];
            }
        }
    }
}

extern "C" void kernel_launch(void* const* d_in, const int* in_sizes, int n_in,
                              void* d_out, int out_size, void* d_ws, size_t ws_size,
                              hipStream_t stream){
    (void)in_sizes; (void)n_in; (void)out_size; (void)ws_size;
    const float* x    = (const float*)d_in[0];
    const float* win  = (const float*)d_in[1];
    const float* cw   = (const float*)d_in[2];
    const float* cb   = (const float*)d_in[3];
    const float* xpw  = (const float*)d_in[4];
    const float* dtw  = (const float*)d_in[5];
    const float* dtb  = (const float*)d_in[6];
    const float* alog = (const float*)d_in[7];
    const float* ds   = (const float*)d_in[8];
    const float* lnw  = (const float*)d_in[9];
    const float* lnb  = (const float*)d_in[10];
    const float* wout = (const float*)d_in[11];

    float* ws    = (float*)d_ws;
    float* xin   = ws + OFF_XIN;
    float* z     = ws + OFF_Z;
    float* xc    = ws + OFF_XC;
    unsigned short* delta = (unsigned short*)(ws + OFF_DELTA);
    float* hloc  = ws + OFF_HLOC;
    float* bc2   = ws + OFF_BC;
    unsigned short* ysb = (unsigned short*)(ws + OFF_YS);
    float* Ssum  = ws + OFF_S;
    unsigned short* winb  = (unsigned short*)(ws + OFF_WB);
    float* cwT   = ws + OFF_CWT;
    unsigned short* wcomb = (unsigned short*)(ws + OFF_WC);
    unsigned short* woutb = (unsigned short*)(ws + OFF_WO);

    k_prep  <<<dim3(672),  dim3(256), 0, stream>>>(win, cw, xpw, dtw, wout, winb, cwT, wcomb, woutb);
    k_inproj<<<dim3(1024), dim3(256), 0, stream>>>(x, winb, xin, z);
    k_conv  <<<dim3(3072), dim3(256), 0, stream>>>(xin, cwT, cb, xc);
    k_xdbl  <<<dim3(256),  dim3(512), 0, stream>>>(xc, wcomb, dtb, delta, bc2);
    k_scanA <<<dim3(2048), dim3(192), 0, stream>>>(delta, bc2, xc, alog, hloc, Ssum);
    k_scanB <<<dim3(192),  dim3(256), 0, stream>>>(hloc, Ssum, alog);
    k_scanC <<<dim3(2048), dim3(192), 0, stream>>>(delta, bc2, xc, alog, hloc, ysb);
    k_fuse  <<<dim3(1024), dim3(256), 0, stream>>>(ysb, xc, z, ds, lnw, lnb, woutb,
                                                   (float*)d_out);
}